// Round 4
// baseline (379.647 us; speedup 1.0000x reference)
//
#include <hip/hip_runtime.h>

#define B_TOTAL 16384
#define F 39
#define E 64
#define U 128

typedef __attribute__((ext_vector_type(8))) short short8;   // 8 bf16
typedef __attribute__((ext_vector_type(4))) float f32x4;

// pack two f32 -> packed bf16 pair (round-half-up)
__device__ __forceinline__ unsigned pack2_bf16(float a, float b) {
  unsigned ua = __builtin_bit_cast(unsigned, a) + 0x8000u;
  unsigned ub = __builtin_bit_cast(unsigned, b) + 0x8000u;
  return (ub & 0xFFFF0000u) | (ua >> 16);
}

// ws layout: wf [0, 1 MiB) ; Fsum [1 MiB, 5 MiB) ; FsumT [5 MiB, 9 MiB)

// ---------------- k1: feat_sum (16 b/block) + W-frag prep ----------------
// grid 1024 x 256. Also writes FsumT for k2's f_i scaling, and wave 0 of
// block bid converts W fragment #bid (64 lanes x 16 B) to bf16 frag order:
// wf[(i*8+ntg)*2+ks][lane] = bf16(W[ntg*16+(lane&15)][i][ks*32+(lane>>4)*8..+7])
__global__ __launch_bounds__(256) void k1(
    const float* __restrict__ embeds, const float* __restrict__ w,
    uint4* __restrict__ wf, float* __restrict__ fsum, float* __restrict__ fsumT) {
  __shared__ __align__(16) float Ft[16 * 68];
  const int t = threadIdx.x, bid = blockIdx.x;
  const int b0 = bid * 16;

  // feat_sum: thread owns (b = t>>4, 4 floats at e4*4)
  const int b = t >> 4, e4 = t & 15;
  const float4* src = (const float4*)(embeds + (size_t)(b0 + b) * (F * E)) + e4;
  float4 s = make_float4(0.f, 0.f, 0.f, 0.f);
  #pragma unroll
  for (int f = 0; f < F; ++f) {
    float4 v = src[f * (E / 4)];
    s.x += v.x; s.y += v.y; s.z += v.z; s.w += v.w;
  }
  *(float4*)&Ft[b * 68 + e4 * 4] = s;
  *(float4*)&fsum[(size_t)(b0 + b) * E + e4 * 4] = s;

  // W-frag prep: wave 0 handles fragment #bid (1024 blocks <-> 1024 frags)
  if (t < 64) {
    const int frag = bid;
    const int ks = frag & 1, ntg = (frag >> 1) & 7, i = frag >> 4;
    const int uu = ntg * 16 + (t & 15), k0 = ks * 32 + (t >> 4) * 8;
    const float* wsrc = w + (size_t)uu * (E * E) + i * E + k0;
    float4 v0 = *(const float4*)wsrc;
    float4 v1 = *(const float4*)(wsrc + 4);
    uint4 o;
    o.x = pack2_bf16(v0.x, v0.y);
    o.y = pack2_bf16(v0.z, v0.w);
    o.z = pack2_bf16(v1.x, v1.y);
    o.w = pack2_bf16(v1.z, v1.w);
    wf[(size_t)frag * 64 + t] = o;
  }
  __syncthreads();

  // transposed writeout: FsumT[e][b0+c*4+r] = Ft[c*4+r][e]
  const int e = t >> 2, c = t & 3;
  float4 o;
  o.x = Ft[(c * 4 + 0) * 68 + e];
  o.y = Ft[(c * 4 + 1) * 68 + e];
  o.z = Ft[(c * 4 + 2) * 68 + e];
  o.w = Ft[(c * 4 + 3) * 68 + e];
  *(float4*)&fsumT[(size_t)e * B_TOTAL + b0 + c * 4] = o;
}

// ---------------- k2: quadratic form via MFMA ----------------
// grid 256 x 512 (8 waves). Wave w covers all 64 b-rows x 16 u-cols
// [w*16, w*16+16) -> block reads each W fragment exactly once (1 MB/block).
// lp[b,u] = sum_i f[b,i] * (sum_k f[b,k] * W[u,i,k])
__global__ __launch_bounds__(512) void k2(
    const uint4* __restrict__ wf, const float* __restrict__ fsum,
    const float* __restrict__ fsumT, float* __restrict__ out) {
  __shared__ __align__(16) float Ft[E * 68];    // [b][e]
  __shared__ __align__(16) float FtT[E * 68];   // [e][b]
  const int t = threadIdx.x;
  const int b0 = blockIdx.x * 64;

  #pragma unroll
  for (int task = t; task < 1024; task += 512) {
    int r = task >> 4, q = task & 15;
    *(float4*)&Ft[r * 68 + q * 4]  = *(const float4*)&fsum[(size_t)(b0 + r) * E + q * 4];
    *(float4*)&FtT[r * 68 + q * 4] = *(const float4*)&fsumT[(size_t)r * B_TOTAL + b0 + q * 4];
  }
  __syncthreads();   // the only barrier

  const int lane = t & 63, wave = t >> 6;
  const int fl = lane & 15;          // A row / C col index
  const int fo = (lane >> 4) * 8;    // k-octet
  const int r0 = (lane >> 4) * 4;    // C row base

  // A-fragments (i-independent): af[mt][ks] = bf16(f[mt*16+fl][ks*32+fo..+7])
  short8 af[4][2];
  #pragma unroll
  for (int mt = 0; mt < 4; ++mt) {
    const float* fr = &Ft[(mt * 16 + fl) * 68];
    #pragma unroll
    for (int ks = 0; ks < 2; ++ks) {
      float4 v0 = *(const float4*)&fr[ks * 32 + fo];
      float4 v1 = *(const float4*)&fr[ks * 32 + fo + 4];
      uint4 o;
      o.x = pack2_bf16(v0.x, v0.y);
      o.y = pack2_bf16(v0.z, v0.w);
      o.z = pack2_bf16(v1.x, v1.y);
      o.w = pack2_bf16(v1.z, v1.w);
      af[mt][ks] = __builtin_bit_cast(short8, o);
    }
  }

  f32x4 acc[4];
  #pragma unroll
  for (int mt = 0; mt < 4; ++mt)
    #pragma unroll
    for (int r = 0; r < 4; ++r) acc[mt][r] = 0.f;

  // frag index for (i, ks) = (i*16 + wave*2 + ks); lane-resolved base:
  const uint4* wv = wf + (size_t)(wave * 2) * 64 + lane;

  #define LOADW(buf, ii) {                 \
    buf[0] = wv[(size_t)((ii) * 16) * 64]; \
    buf[1] = wv[(size_t)((ii) * 16 + 1) * 64]; }

  #define STEP(ii, buf) {                                                   \
    short8 bf0 = __builtin_bit_cast(short8, buf[0]);                        \
    short8 bf1 = __builtin_bit_cast(short8, buf[1]);                        \
    _Pragma("unroll")                                                       \
    for (int mt = 0; mt < 4; ++mt) {                                        \
      f32x4 s = {0.f, 0.f, 0.f, 0.f};                                       \
      s = __builtin_amdgcn_mfma_f32_16x16x32_bf16(af[mt][0], bf0, s, 0, 0, 0); \
      s = __builtin_amdgcn_mfma_f32_16x16x32_bf16(af[mt][1], bf1, s, 0, 0, 0); \
      f32x4 fi = *(const f32x4*)&FtT[(ii) * 68 + mt * 16 + r0];             \
      acc[mt] += fi * s;                                                    \
    } }

  uint4 wa[2], wb[2], wc[2], wd[2];
  LOADW(wa, 0);
  LOADW(wb, 1);
  for (int i = 0; i < E; i += 4) {
    LOADW(wc, i + 2);
    STEP(i, wa);
    LOADW(wd, i + 3);
    STEP(i + 1, wb);
    if (i + 4 < E) LOADW(wa, i + 4);
    STEP(i + 2, wc);
    if (i + 5 < E) LOADW(wb, i + 5);
    STEP(i + 3, wd);
  }

  // Epilogue: C/D layout col=lane&15 (u), row=(lane>>4)*4+r (b)
  #pragma unroll
  for (int mt = 0; mt < 4; ++mt)
    #pragma unroll
    for (int r = 0; r < 4; ++r)
      out[(size_t)(b0 + mt * 16 + r0 + r) * U + wave * 16 + fl] = acc[mt][r];
}

extern "C" void kernel_launch(void* const* d_in, const int* in_sizes, int n_in,
                              void* d_out, int out_size, void* d_ws, size_t ws_size,
                              hipStream_t stream) {
  const float* embeds = (const float*)d_in[0];
  const float* w      = (const float*)d_in[1];
  float* out          = (float*)d_out;
  char* ws            = (char*)d_ws;
  uint4* wf    = (uint4*)ws;                        // 1 MiB
  float* fsum  = (float*)(ws + (1u << 20));         // 4 MiB
  float* fsumT = (float*)(ws + (5u << 20));         // 4 MiB
  k1<<<dim3(1024), dim3(256), 0, stream>>>(embeds, w, wf, fsum, fsumT);
  k2<<<dim3(B_TOTAL / 64), dim3(512), 0, stream>>>(wf, fsum, fsumT, out);
}

// Round 5
// 253.710 us; speedup vs baseline: 1.4964x; 1.4964x over previous
//
#include <hip/hip_runtime.h>

#define B_TOTAL 16384
#define F 39
#define E 64
#define U 128
#define BT 64
#define THREADS 512      // 8 waves

typedef __attribute__((ext_vector_type(8))) short short8;   // 8 bf16
typedef __attribute__((ext_vector_type(4))) float f32x4;

// pack two f32 -> packed bf16 pair (round-half-up)
__device__ __forceinline__ unsigned pack2_bf16(float a, float b) {
  unsigned ua = __builtin_bit_cast(unsigned, a) + 0x8000u;
  unsigned ub = __builtin_bit_cast(unsigned, b) + 0x8000u;
  return (ub & 0xFFFF0000u) | (ua >> 16);
}

// ---- prep: W (U,E,E) f32 -> fragment-ordered bf16 in ws (1 MiB) ----
// wf[(i*8+ntg)*2+ks][lane] (16 B) = bf16(W[ntg*16+(lane&15)][i][ks*32+(lane>>4)*8 .. +7])
__global__ __launch_bounds__(256) void prep_w(const float* __restrict__ w,
                                              uint4* __restrict__ wf) {
  int tid = blockIdx.x * 256 + threadIdx.x;   // 65536 = 1024 frags * 64 lanes
  int lane = tid & 63;
  int frag = tid >> 6;
  int ks  = frag & 1;
  int ntg = (frag >> 1) & 7;
  int i   = frag >> 4;
  int uu  = ntg * 16 + (lane & 15);
  int k0  = ks * 32 + (lane >> 4) * 8;
  const float* src = w + (size_t)uu * (E * E) + i * E + k0;
  float4 v0 = *(const float4*)src;
  float4 v1 = *(const float4*)(src + 4);
  uint4 o;
  o.x = pack2_bf16(v0.x, v0.y);
  o.y = pack2_bf16(v0.z, v0.w);
  o.z = pack2_bf16(v1.x, v1.y);
  o.w = pack2_bf16(v1.z, v1.w);
  wf[tid] = o;
}

// ---- fused: feat_sum (phase 1, HBM-bound) + quadratic form via MFMA ----
// grid 256 x 512. Wave w owns u-cols [w*16, w*16+16): block reads each W
// fragment exactly once (1 MB/block). lp[b,u] = sum_i f[b,i]*(sum_k f[b,k]*W[u,i,k])
__global__ __launch_bounds__(THREADS) void fused_outer(
    const float* __restrict__ embeds, const uint4* __restrict__ wf,
    float* __restrict__ out) {
  __shared__ __align__(16) float Ft[BT * 68];   // [b][e]
  __shared__ __align__(16) float FtT[E * 68];   // [e][b]

  const int t = threadIdx.x;
  const int b0 = blockIdx.x * BT;

  // ---------------- Phase 1: feat_sum over F ----------------
  #pragma unroll
  for (int task = t; task < BT * 16; task += THREADS) {
    int b = task >> 4, e4 = task & 15;
    const float4* src = (const float4*)(embeds + (size_t)(b0 + b) * (F * E)) + e4;
    float4 s = make_float4(0.f, 0.f, 0.f, 0.f);
    #pragma unroll
    for (int f = 0; f < F; ++f) {
      float4 v = src[f * (E / 4)];
      s.x += v.x; s.y += v.y; s.z += v.z; s.w += v.w;
    }
    *(float4*)&Ft[b * 68 + e4 * 4] = s;
    FtT[(e4 * 4 + 0) * 68 + b] = s.x;
    FtT[(e4 * 4 + 1) * 68 + b] = s.y;
    FtT[(e4 * 4 + 2) * 68 + b] = s.z;
    FtT[(e4 * 4 + 3) * 68 + b] = s.w;
  }

  const int lane = t & 63, wave = t >> 6;
  const int fl = lane & 15;          // A row / C col index
  const int fo = (lane >> 4) * 8;    // k-octet
  const int r0 = (lane >> 4) * 4;    // C row base

  // frag index for (i, ks) = i*16 + wave*2 + ks; lane-resolved base:
  const uint4* wv = wf + (size_t)(wave * 2) * 64 + lane;

  #define LOADW(buf, ii) {                 \
    buf[0] = wv[(size_t)((ii) * 16) * 64]; \
    buf[1] = wv[(size_t)((ii) * 16 + 1) * 64]; }

  // depth-4 register pipeline; issue the first 4 BEFORE the barrier so the
  // loads are in flight while phase 1 drains.
  uint4 w0[2], w1[2], w2[2], w3[2];
  LOADW(w0, 0);
  LOADW(w1, 1);
  LOADW(w2, 2);
  LOADW(w3, 3);
  __syncthreads();   // the only barrier

  // A-fragments (i-independent): af[mt][ks] = bf16(f[mt*16+fl][ks*32+fo..+7])
  short8 af[4][2];
  #pragma unroll
  for (int mt = 0; mt < 4; ++mt) {
    const float* fr = &Ft[(mt * 16 + fl) * 68];
    #pragma unroll
    for (int ks = 0; ks < 2; ++ks) {
      float4 v0 = *(const float4*)&fr[ks * 32 + fo];
      float4 v1 = *(const float4*)&fr[ks * 32 + fo + 4];
      uint4 o;
      o.x = pack2_bf16(v0.x, v0.y);
      o.y = pack2_bf16(v0.z, v0.w);
      o.z = pack2_bf16(v1.x, v1.y);
      o.w = pack2_bf16(v1.z, v1.w);
      af[mt][ks] = __builtin_bit_cast(short8, o);
    }
  }

  f32x4 acc[4];
  #pragma unroll
  for (int mt = 0; mt < 4; ++mt)
    #pragma unroll
    for (int r = 0; r < 4; ++r) acc[mt][r] = 0.f;

  #define STEP(ii, buf) {                                                      \
    short8 bf0 = __builtin_bit_cast(short8, buf[0]);                           \
    short8 bf1 = __builtin_bit_cast(short8, buf[1]);                           \
    _Pragma("unroll")                                                          \
    for (int mt = 0; mt < 4; ++mt) {                                           \
      f32x4 s = {0.f, 0.f, 0.f, 0.f};                                          \
      s = __builtin_amdgcn_mfma_f32_16x16x32_bf16(af[mt][0], bf0, s, 0, 0, 0); \
      s = __builtin_amdgcn_mfma_f32_16x16x32_bf16(af[mt][1], bf1, s, 0, 0, 0); \
      f32x4 fi = *(const f32x4*)&FtT[(ii) * 68 + mt * 16 + r0];                \
      acc[mt] += fi * s;                                                       \
    } }

  // K-loop: no barriers. Tail prefetches read dead ws past wf (unused, legal).
  for (int i = 0; i < E; i += 4) {
    STEP(i, w0);     LOADW(w0, i + 4);
    STEP(i + 1, w1); LOADW(w1, i + 5);
    STEP(i + 2, w2); LOADW(w2, i + 6);
    STEP(i + 3, w3); LOADW(w3, i + 7);
  }

  // Epilogue: C/D layout col=lane&15 (u), row=(lane>>4)*4+r (b)
  #pragma unroll
  for (int mt = 0; mt < 4; ++mt)
    #pragma unroll
    for (int r = 0; r < 4; ++r)
      out[(size_t)(b0 + mt * 16 + r0 + r) * U + wave * 16 + fl] = acc[mt][r];
  #undef LOADW
  #undef STEP
}

extern "C" void kernel_launch(void* const* d_in, const int* in_sizes, int n_in,
                              void* d_out, int out_size, void* d_ws, size_t ws_size,
                              hipStream_t stream) {
  const float* embeds = (const float*)d_in[0];
  const float* w      = (const float*)d_in[1];
  float* out          = (float*)d_out;
  uint4* wf           = (uint4*)d_ws;   // 1 MiB used (+128 KiB dead-read slack)
  prep_w<<<dim3(256), dim3(256), 0, stream>>>(w, wf);
  fused_outer<<<dim3(B_TOTAL / BT), dim3(THREADS), 0, stream>>>(embeds, wf, out);
}

// Round 6
// 235.985 us; speedup vs baseline: 1.6088x; 1.0751x over previous
//
#include <hip/hip_runtime.h>

#define B_TOTAL 16384
#define F 39
#define E 64
#define U 128
#define BT 64
#define THREADS 512      // 8 waves

typedef __attribute__((ext_vector_type(8))) short short8;   // 8 bf16
typedef __attribute__((ext_vector_type(4))) float f32x4;
typedef __attribute__((ext_vector_type(4))) unsigned u32x4;

// pack two f32 -> packed bf16 pair (round-half-up)
__device__ __forceinline__ unsigned pack2_bf16(float a, float b) {
  unsigned ua = __builtin_bit_cast(unsigned, a) + 0x8000u;
  unsigned ub = __builtin_bit_cast(unsigned, b) + 0x8000u;
  return (ub & 0xFFFF0000u) | (ua >> 16);
}

// ---- prep: W (U,E,E) f32 -> fragment-ordered bf16 in ws (1 MiB) ----
// wf[(i*8+ntg)*2+ks][lane] (16 B) = bf16(W[ntg*16+(lane&15)][i][ks*32+(lane>>4)*8 .. +7])
__global__ __launch_bounds__(256) void prep_w(const float* __restrict__ w,
                                              u32x4* __restrict__ wf) {
  int tid = blockIdx.x * 256 + threadIdx.x;   // 65536 = 1024 frags * 64 lanes
  int lane = tid & 63;
  int frag = tid >> 6;
  int ks  = frag & 1;
  int ntg = (frag >> 1) & 7;
  int i   = frag >> 4;
  int uu  = ntg * 16 + (lane & 15);
  int k0  = ks * 32 + (lane >> 4) * 8;
  const f32x4* src = (const f32x4*)(w + (size_t)uu * (E * E) + i * E + k0);
  f32x4 v0 = __builtin_nontemporal_load(src);
  f32x4 v1 = __builtin_nontemporal_load(src + 1);
  u32x4 o;
  o[0] = pack2_bf16(v0[0], v0[1]);
  o[1] = pack2_bf16(v0[2], v0[3]);
  o[2] = pack2_bf16(v1[0], v1[1]);
  o[3] = pack2_bf16(v1[2], v1[3]);
  wf[tid] = o;   // normal store: wf must be L2-resident for fused_outer
}

// ---- fused: feat_sum (phase 1, HBM-bound) + quadratic form via MFMA ----
// grid 256 x 512. Wave w owns u-cols [w*16, w*16+16): block reads each W
// fragment exactly once (1 MB/block). lp[b,u] = sum_i f[b,i]*(sum_k f[b,k]*W[u,i,k])
__global__ __launch_bounds__(THREADS) void fused_outer(
    const float* __restrict__ embeds, const u32x4* __restrict__ wf,
    float* __restrict__ out) {
  __shared__ __align__(16) float Ft[BT * 68];   // [b][e]
  __shared__ __align__(16) float FtT[E * 68];   // [e][b]

  const int t = threadIdx.x;
  const int b0 = blockIdx.x * BT;

  // ---------------- Phase 1: feat_sum over F ----------------
  // Non-temporal: embeds is streamed once; do NOT allocate into L2/L3 (the
  // harness's 654 MB ws-poison fill leaves the caches full of dirty lines --
  // allocating reads force concurrent writebacks and halve our read BW).
  #pragma unroll
  for (int task = t; task < BT * 16; task += THREADS) {
    int b = task >> 4, e4 = task & 15;
    const f32x4* src = (const f32x4*)(embeds + (size_t)(b0 + b) * (F * E)) + e4;
    f32x4 s = {0.f, 0.f, 0.f, 0.f};
    #pragma unroll
    for (int f = 0; f < F; ++f) {
      f32x4 v = __builtin_nontemporal_load(src + f * (E / 4));
      s += v;
    }
    *(f32x4*)&Ft[b * 68 + e4 * 4] = s;
    FtT[(e4 * 4 + 0) * 68 + b] = s[0];
    FtT[(e4 * 4 + 1) * 68 + b] = s[1];
    FtT[(e4 * 4 + 2) * 68 + b] = s[2];
    FtT[(e4 * 4 + 3) * 68 + b] = s[3];
  }

  const int lane = t & 63, wave = t >> 6;
  const int fl = lane & 15;          // A row / C col index
  const int fo = (lane >> 4) * 8;    // k-octet
  const int r0 = (lane >> 4) * 4;    // C row base

  // frag index for (i, ks) = i*16 + wave*2 + ks; lane-resolved base:
  const u32x4* wv = wf + (size_t)(wave * 2) * 64 + lane;

  #define LOADW(buf, ii) {                 \
    buf[0] = wv[(size_t)((ii) * 16) * 64]; \
    buf[1] = wv[(size_t)((ii) * 16 + 1) * 64]; }

  // depth-4 register pipeline; issue the first 4 BEFORE the barrier so the
  // loads are in flight while phase 1 drains.
  u32x4 w0[2], w1[2], w2[2], w3[2];
  LOADW(w0, 0);
  LOADW(w1, 1);
  LOADW(w2, 2);
  LOADW(w3, 3);
  __syncthreads();   // the only barrier

  // A-fragments (i-independent): af[mt][ks] = bf16(f[mt*16+fl][ks*32+fo..+7])
  short8 af[4][2];
  #pragma unroll
  for (int mt = 0; mt < 4; ++mt) {
    const float* fr = &Ft[(mt * 16 + fl) * 68];
    #pragma unroll
    for (int ks = 0; ks < 2; ++ks) {
      f32x4 v0 = *(const f32x4*)&fr[ks * 32 + fo];
      f32x4 v1 = *(const f32x4*)&fr[ks * 32 + fo + 4];
      u32x4 o;
      o[0] = pack2_bf16(v0[0], v0[1]);
      o[1] = pack2_bf16(v0[2], v0[3]);
      o[2] = pack2_bf16(v1[0], v1[1]);
      o[3] = pack2_bf16(v1[2], v1[3]);
      af[mt][ks] = __builtin_bit_cast(short8, o);
    }
  }

  f32x4 acc[4];
  #pragma unroll
  for (int mt = 0; mt < 4; ++mt)
    #pragma unroll
    for (int r = 0; r < 4; ++r) acc[mt][r] = 0.f;

  #define STEP(ii, buf) {                                                      \
    short8 bf0 = __builtin_bit_cast(short8, buf[0]);                           \
    short8 bf1 = __builtin_bit_cast(short8, buf[1]);                           \
    _Pragma("unroll")                                                          \
    for (int mt = 0; mt < 4; ++mt) {                                           \
      f32x4 s = {0.f, 0.f, 0.f, 0.f};                                          \
      s = __builtin_amdgcn_mfma_f32_16x16x32_bf16(af[mt][0], bf0, s, 0, 0, 0); \
      s = __builtin_amdgcn_mfma_f32_16x16x32_bf16(af[mt][1], bf1, s, 0, 0, 0); \
      f32x4 fi = *(const f32x4*)&FtT[(ii) * 68 + mt * 16 + r0];                \
      acc[mt] += fi * s;                                                       \
    } }

  // K-loop: no barriers. Tail prefetches read dead ws past wf (unused, legal).
  for (int i = 0; i < E; i += 4) {
    STEP(i, w0);     LOADW(w0, i + 4);
    STEP(i + 1, w1); LOADW(w1, i + 5);
    STEP(i + 2, w2); LOADW(w2, i + 6);
    STEP(i + 3, w3); LOADW(w3, i + 7);
  }

  // Epilogue: C/D layout col=lane&15 (u), row=(lane>>4)*4+r (b).
  // Non-temporal: out is never re-read by us; don't evict L2 for it.
  #pragma unroll
  for (int mt = 0; mt < 4; ++mt)
    #pragma unroll
    for (int r = 0; r < 4; ++r)
      __builtin_nontemporal_store(
          acc[mt][r],
          &out[(size_t)(b0 + mt * 16 + r0 + r) * U + wave * 16 + fl]);
  #undef LOADW
  #undef STEP
}

extern "C" void kernel_launch(void* const* d_in, const int* in_sizes, int n_in,
                              void* d_out, int out_size, void* d_ws, size_t ws_size,
                              hipStream_t stream) {
  const float* embeds = (const float*)d_in[0];
  const float* w      = (const float*)d_in[1];
  float* out          = (float*)d_out;
  u32x4* wf           = (u32x4*)d_ws;   // 1 MiB used (+128 KiB dead-read slack)
  prep_w<<<dim3(256), dim3(256), 0, stream>>>(w, wf);
  fused_outer<<<dim3(B_TOTAL / BT), dim3(THREADS), 0, stream>>>(embeds, wf, out);
}

// Round 7
// 232.978 us; speedup vs baseline: 1.6295x; 1.0129x over previous
//
#include <hip/hip_runtime.h>

#define B_TOTAL 16384
#define F 39
#define E 64
#define U 128
#define BT 64
#define THREADS 1024     // 16 waves: 8 u-col groups x 2 k-halves (split-K)

typedef __attribute__((ext_vector_type(8))) short short8;   // 8 bf16
typedef __attribute__((ext_vector_type(4))) float f32x4;
typedef __attribute__((ext_vector_type(4))) unsigned u32x4;

// pack two f32 -> packed bf16 pair (round-half-up)
__device__ __forceinline__ unsigned pack2_bf16(float a, float b) {
  unsigned ua = __builtin_bit_cast(unsigned, a) + 0x8000u;
  unsigned ub = __builtin_bit_cast(unsigned, b) + 0x8000u;
  return (ub & 0xFFFF0000u) | (ua >> 16);
}

// ---- prep: W (U,E,E) f32 -> fragment-ordered bf16 in ws (1 MiB) ----
// wf[(i*8+ntg)*2+ks][lane] (16 B) = bf16(W[ntg*16+(lane&15)][i][ks*32+(lane>>4)*8 .. +7])
__global__ __launch_bounds__(256) void prep_w(const float* __restrict__ w,
                                              u32x4* __restrict__ wf) {
  int tid = blockIdx.x * 256 + threadIdx.x;   // 65536 = 1024 frags * 64 lanes
  int lane = tid & 63;
  int frag = tid >> 6;
  int ks  = frag & 1;
  int ntg = (frag >> 1) & 7;
  int i   = frag >> 4;
  int uu  = ntg * 16 + (lane & 15);
  int k0  = ks * 32 + (lane >> 4) * 8;
  const f32x4* src = (const f32x4*)(w + (size_t)uu * (E * E) + i * E + k0);
  f32x4 v0 = __builtin_nontemporal_load(src);
  f32x4 v1 = __builtin_nontemporal_load(src + 1);
  u32x4 o;
  o[0] = pack2_bf16(v0[0], v0[1]);
  o[1] = pack2_bf16(v0[2], v0[3]);
  o[2] = pack2_bf16(v1[0], v1[1]);
  o[3] = pack2_bf16(v1[2], v1[3]);
  wf[tid] = o;   // normal store: wf should be L2-resident for fused_outer
}

// ---- fused: feat_sum (phase 1) + quadratic form via MFMA, split-K ----
// grid 256 x 1024. Wave (uc, kh): uc owns u-cols [uc*16,uc*16+16), kh owns
// i-half [kh*32, kh*32+32). Each W fragment read exactly once per block.
// lp[b,u] = sum_i f[b,i] * (sum_k f[b,k] * W[u,i,k])
__global__ __launch_bounds__(THREADS) void fused_outer(
    const float* __restrict__ embeds, const u32x4* __restrict__ wf,
    float* __restrict__ out) {
  // smem0 aliases: Ft [64][68] f32 (phase1 .. af-build), then split-K partials
  // [8 uc][64 lane][4 mt] f32x4 (after K-loop). Barrier2 separates lifetimes.
  __shared__ __align__(16) char smem0[32768];
  __shared__ __align__(16) float FtT[E * 68];   // [e][b], live whole kernel
  float* Ft  = (float*)smem0;
  f32x4* prt = (f32x4*)smem0;

  const int t = threadIdx.x;
  const int b0 = blockIdx.x * BT;

  // ---------------- Phase 1: feat_sum over F (one task per thread) --------
  // NT loads: embeds streamed once; don't allocate into poisoned L2/L3.
  {
    const int b = t >> 4, e4 = t & 15;
    const f32x4* src = (const f32x4*)(embeds + (size_t)(b0 + b) * (F * E)) + e4;
    f32x4 s = {0.f, 0.f, 0.f, 0.f};
    #pragma unroll
    for (int f = 0; f < F; ++f)
      s += __builtin_nontemporal_load(src + f * (E / 4));
    *(f32x4*)&Ft[b * 68 + e4 * 4] = s;
    FtT[(e4 * 4 + 0) * 68 + b] = s[0];
    FtT[(e4 * 4 + 1) * 68 + b] = s[1];
    FtT[(e4 * 4 + 2) * 68 + b] = s[2];
    FtT[(e4 * 4 + 3) * 68 + b] = s[3];
  }

  const int lane = t & 63, wave = t >> 6;
  const int uc = wave & 7;           // u-col group: cols [uc*16, uc*16+16)
  const int kh = wave >> 3;          // i-half: [kh*32, kh*32+32)
  const int fl = lane & 15;          // A row / C col index
  const int fo = (lane >> 4) * 8;    // k-octet
  const int r0 = (lane >> 4) * 4;    // C row base

  // frag index for (i, ks) = i*16 + uc*2 + ks; lane-resolved base:
  const u32x4* wv = wf + (size_t)(uc * 2) * 64 + lane;

  #define LOADW(buf, ii) {                 \
    buf[0] = wv[(size_t)((ii) * 16) * 64]; \
    buf[1] = wv[(size_t)((ii) * 16 + 1) * 64]; }

  // depth-4 register pipeline; first 4 issued BEFORE the barrier.
  const int i0 = kh * 32;
  u32x4 w0[2], w1[2], w2[2], w3[2];
  LOADW(w0, i0);
  LOADW(w1, i0 + 1);
  LOADW(w2, i0 + 2);
  LOADW(w3, i0 + 3);
  __syncthreads();   // barrier1: Ft/FtT ready

  // A-fragments (i-independent): af[mt][ks] = bf16(f[mt*16+fl][ks*32+fo..+7])
  short8 af[4][2];
  #pragma unroll
  for (int mt = 0; mt < 4; ++mt) {
    const float* fr = &Ft[(mt * 16 + fl) * 68];
    #pragma unroll
    for (int ks = 0; ks < 2; ++ks) {
      f32x4 v0 = *(const f32x4*)&fr[ks * 32 + fo];
      f32x4 v1 = *(const f32x4*)&fr[ks * 32 + fo + 4];
      u32x4 o;
      o[0] = pack2_bf16(v0[0], v0[1]);
      o[1] = pack2_bf16(v0[2], v0[3]);
      o[2] = pack2_bf16(v1[0], v1[1]);
      o[3] = pack2_bf16(v1[2], v1[3]);
      af[mt][ks] = __builtin_bit_cast(short8, o);
    }
  }
  __syncthreads();   // barrier2: all Ft reads done; smem0 becomes 'prt'

  f32x4 acc[4];
  #pragma unroll
  for (int mt = 0; mt < 4; ++mt)
    #pragma unroll
    for (int r = 0; r < 4; ++r) acc[mt][r] = 0.f;

  #define STEP(ii, buf) {                                                      \
    short8 bf0 = __builtin_bit_cast(short8, buf[0]);                           \
    short8 bf1 = __builtin_bit_cast(short8, buf[1]);                           \
    _Pragma("unroll")                                                          \
    for (int mt = 0; mt < 4; ++mt) {                                           \
      f32x4 s = {0.f, 0.f, 0.f, 0.f};                                          \
      s = __builtin_amdgcn_mfma_f32_16x16x32_bf16(af[mt][0], bf0, s, 0, 0, 0); \
      s = __builtin_amdgcn_mfma_f32_16x16x32_bf16(af[mt][1], bf1, s, 0, 0, 0); \
      f32x4 fi = *(const f32x4*)&FtT[(ii) * 68 + mt * 16 + r0];                \
      acc[mt] += fi * s;                                                       \
    } }

  // K-loop (32 steps per wave): no barriers. Tail prefetches read dead ws
  // past wf (max ~1.2 MiB into ws; unused, legal).
  for (int i = i0; i < i0 + 32; i += 4) {
    STEP(i, w0);     LOADW(w0, i + 4);
    STEP(i + 1, w1); LOADW(w1, i + 5);
    STEP(i + 2, w2); LOADW(w2, i + 6);
    STEP(i + 3, w3); LOADW(w3, i + 7);
  }

  // ---------------- split-K combine + epilogue ----------------
  if (kh == 1) {
    #pragma unroll
    for (int mt = 0; mt < 4; ++mt)
      prt[(uc * 64 + lane) * 4 + mt] = acc[mt];
  }
  __syncthreads();   // barrier3
  if (kh == 0) {
    // C/D layout col=lane&15 (u), row=(lane>>4)*4+r (b)
    #pragma unroll
    for (int mt = 0; mt < 4; ++mt) {
      f32x4 v = acc[mt] + prt[(uc * 64 + lane) * 4 + mt];
      #pragma unroll
      for (int r = 0; r < 4; ++r)
        __builtin_nontemporal_store(
            v[r], &out[(size_t)(b0 + mt * 16 + r0 + r) * U + uc * 16 + fl]);
    }
  }
  #undef LOADW
  #undef STEP
}

extern "C" void kernel_launch(void* const* d_in, const int* in_sizes, int n_in,
                              void* d_out, int out_size, void* d_ws, size_t ws_size,
                              hipStream_t stream) {
  const float* embeds = (const float*)d_in[0];
  const float* w      = (const float*)d_in[1];
  float* out          = (float*)d_out;
  u32x4* wf           = (u32x4*)d_ws;   // 1 MiB used (+ dead-read slack)
  prep_w<<<dim3(256), dim3(256), 0, stream>>>(w, wf);
  fused_outer<<<dim3(B_TOTAL / BT), dim3(THREADS), 0, stream>>>(embeds, wf, out);
}